// Round 3
// baseline (48.019 us; speedup 1.0000x reference)
//
#include <hip/hip_runtime.h>

// Problem: N=64 graphs, K=64 nodes, C_IN=128, C=128, fp32.
// Pipeline (3 launches):
//   K1: h = x @ W_lin[:, :128].T + b_lin + t*W_lin[:,128]
//   K2f: heterogeneous grid: T = tanh(h@Wu1.T+bu1)  and
//        S' = (sum_{i!=j} tanh(A_j + Bb_i))/64 computed graph-locally
//        (A = h@Wb1L.T, Bb = h@Wb1R.T + bb1 live only in LDS)
//   K4: out = T@Wu2.T + S'@Wb2.T + bu2 + (63/64)*bb2
#define LS 132   // LDS row stride (dwords) for 128-k tiles: (4l)%32 -> 8 quads, min cycles
#define LS4 268  // stride for 256-k tiles: (12l)%32 -> 8 quads (264 would be 2x conflict)
#define ROW_ELEMS 524288  // 4096*128

__device__ __forceinline__ float sigterm(float x) {
    // 1/(exp(2x)+1); tanh(x) = 1 - 2*sigterm(x)
    float e = __builtin_amdgcn_exp2f(x * 2.8853900817779268f);
    return __builtin_amdgcn_rcpf(e + 1.0f);
}
__device__ __forceinline__ float tanh_fast(float x) {
    return 1.0f - 2.0f * sigterm(x);
}

// Stage 64 rows x 128 cols of X (row stride 128) into xs[64][lsk] at col coff.
__device__ __forceinline__ void stage64(const float* __restrict__ X, int r0,
                                        float* __restrict__ xs, int tid,
                                        int lsk, int coff) {
    const float4* src = reinterpret_cast<const float4*>(X + (size_t)r0 * 128);
#pragma unroll
    for (int p = 0; p < 8; ++p) {
        const int q = p * 256 + tid;  // 2048 float4s
        const int r = q >> 5;
        const int k4 = (q & 31) << 2;
        *reinterpret_cast<float4*>(&xs[r * lsk + coff + k4]) = src[q];
    }
}

// 128-k inner product: lane's row (LDS, per-lane b128) dotted with NC
// wave-uniform weight rows (scalarized to s_load by uniformity).
template <int NC>
__device__ __forceinline__ void accum(const float* __restrict__ xs, int lane,
                                      int lsk, int kbase,
                                      const float* const (&wrow)[NC],
                                      float (&acc)[NC]) {
#pragma unroll 4
    for (int kq = 0; kq < 32; ++kq) {
        const float4 a = *reinterpret_cast<const float4*>(
            &xs[lane * lsk + kbase + kq * 4]);
#pragma unroll
        for (int c = 0; c < NC; ++c) {
            const float* w = wrow[c] + kq * 4;
            acc[c] = fmaf(a.x, w[0], acc[c]);
            acc[c] = fmaf(a.y, w[1], acc[c]);
            acc[c] = fmaf(a.z, w[2], acc[c]);
            acc[c] = fmaf(a.w, w[3], acc[c]);
        }
    }
}

// K1: h = x@W_lin[:,:128].T + b_lin + t*W_lin[:,128]. 4 cols/wave.
__global__ __launch_bounds__(256) void k1_h(const float* __restrict__ x,
                                            const float* __restrict__ W_lin,
                                            const float* __restrict__ b_lin,
                                            const float* __restrict__ tp,
                                            float* __restrict__ h) {
    __shared__ float xs[64 * LS];
    const int tid = threadIdx.x;
    const int lane = tid & 63;
    const int wv = __builtin_amdgcn_readfirstlane(tid >> 6);
    const int r0 = blockIdx.y * 64;
    const int cg = blockIdx.x * 16 + wv * 4;
    stage64(x, r0, xs, tid, LS, 0);
    __syncthreads();
    float acc[4] = {0.f, 0.f, 0.f, 0.f};
    const float* wrow[4];
#pragma unroll
    for (int c = 0; c < 4; ++c) wrow[c] = W_lin + (cg + c) * 129;
    accum<4>(xs, lane, LS, 0, wrow, acc);
    const float tv = tp[0];
    float4 o;
    o.x = acc[0] + b_lin[cg + 0] + tv * W_lin[(cg + 0) * 129 + 128];
    o.y = acc[1] + b_lin[cg + 1] + tv * W_lin[(cg + 1) * 129 + 128];
    o.z = acc[2] + b_lin[cg + 2] + tv * W_lin[(cg + 2) * 129 + 128];
    o.w = acc[3] + b_lin[cg + 3] + tv * W_lin[(cg + 3) * 129 + 128];
    *reinterpret_cast<float4*>(&h[(size_t)(r0 + lane) * 128 + cg]) = o;
}

// K2f: blockIdx.x < 4  -> T cols (32/block, 8/wave)
//      blockIdx.x >= 4 -> binary chunk of 16 channels for graph blockIdx.y:
//        waves 0,1 compute A cols, waves 2,3 compute Bb cols (into LDS),
//        then all 4 waves do the 64-i sigterm sum for 4 channels each.
#define BSTR 20  // as/bs row stride (dwords): (20l)%32 covers 8 quads
__global__ __launch_bounds__(256) void k2_fused(
    const float* __restrict__ h, const float* __restrict__ Wu1,
    const float* __restrict__ bu1, const float* __restrict__ Wb1,
    const float* __restrict__ bb1, float* __restrict__ T,
    float* __restrict__ S) {
    __shared__ float xs[64 * LS];
    __shared__ float as[64 * BSTR];
    __shared__ float bs[64 * BSTR];
    const int tid = threadIdx.x;
    const int lane = tid & 63;
    const int wv = __builtin_amdgcn_readfirstlane(tid >> 6);
    const int r0 = blockIdx.y * 64;  // graph n * 64
    const int bx = blockIdx.x;
    stage64(h, r0, xs, tid, LS, 0);
    __syncthreads();

    if (bx < 4) {  // ---- unary T ----
        const int cg = bx * 32 + wv * 8;
        float acc[8] = {0.f, 0.f, 0.f, 0.f, 0.f, 0.f, 0.f, 0.f};
        const float* wrow[8];
#pragma unroll
        for (int c = 0; c < 8; ++c) wrow[c] = Wu1 + (cg + c) * 128;
        accum<8>(xs, lane, LS, 0, wrow, acc);
        float4 v0, v1;
        v0.x = tanh_fast(acc[0] + bu1[cg + 0]);
        v0.y = tanh_fast(acc[1] + bu1[cg + 1]);
        v0.z = tanh_fast(acc[2] + bu1[cg + 2]);
        v0.w = tanh_fast(acc[3] + bu1[cg + 3]);
        v1.x = tanh_fast(acc[4] + bu1[cg + 4]);
        v1.y = tanh_fast(acc[5] + bu1[cg + 5]);
        v1.z = tanh_fast(acc[6] + bu1[cg + 6]);
        v1.w = tanh_fast(acc[7] + bu1[cg + 7]);
        float* dst = T + (size_t)(r0 + lane) * 128 + cg;
        *reinterpret_cast<float4*>(dst) = v0;
        *reinterpret_cast<float4*>(dst + 4) = v1;
    } else {  // ---- binary chunk ----
        const int cb = (bx - 4) * 16;
        const bool isB = wv >= 2;
        const int half = wv & 1;              // which 8-col half of the chunk
        const int c0 = cb + half * 8;         // global GEMM col base
        float acc[8] = {0.f, 0.f, 0.f, 0.f, 0.f, 0.f, 0.f, 0.f};
        const float* wrow[8];
#pragma unroll
        for (int c = 0; c < 8; ++c)
            wrow[c] = Wb1 + (c0 + c) * 256 + (isB ? 128 : 0);
        accum<8>(xs, lane, LS, 0, wrow, acc);
        if (isB) {
#pragma unroll
            for (int c = 0; c < 8; ++c) acc[c] += bb1[c0 + c];
        }
        float* dstl = (isB ? bs : as) + lane * BSTR + half * 8;
        float4 v0 = {acc[0], acc[1], acc[2], acc[3]};
        float4 v1 = {acc[4], acc[5], acc[6], acc[7]};
        *reinterpret_cast<float4*>(dstl) = v0;
        *reinterpret_cast<float4*>(dstl + 4) = v1;
        __syncthreads();  // block-uniform branch: all 4 waves arrive

        // S' phase: this wave handles 4 channels lc..lc+3 of the chunk.
        const int lc = wv * 4;
        const float4 a = *reinterpret_cast<const float4*>(&as[lane * BSTR + lc]);
        float s0 = 0.f, s1 = 0.f, s2 = 0.f, s3 = 0.f;
#pragma unroll 8
        for (int i = 0; i < 64; ++i) {
            const float4 b = *reinterpret_cast<const float4*>(&bs[i * BSTR + lc]);
            s0 += sigterm(a.x + b.x);
            s1 += sigterm(a.y + b.y);
            s2 += sigterm(a.z + b.z);
            s3 += sigterm(a.w + b.w);
        }
        const float4 bj = *reinterpret_cast<const float4*>(&bs[lane * BSTR + lc]);
        float4 o;
        o.x = (63.0f - 2.0f * (s0 - sigterm(a.x + bj.x))) * 0.015625f;
        o.y = (63.0f - 2.0f * (s1 - sigterm(a.y + bj.y))) * 0.015625f;
        o.z = (63.0f - 2.0f * (s2 - sigterm(a.z + bj.z))) * 0.015625f;
        o.w = (63.0f - 2.0f * (s3 - sigterm(a.w + bj.w))) * 0.015625f;
        *reinterpret_cast<float4*>(&S[(size_t)(r0 + lane) * 128 + cb + lc]) = o;
    }
}

// K4: out = T@Wu2.T + S'@Wb2.T + bu2 + (63/64)*bb2. One 256-k accumulation:
// stage T into cols [0,128) and S' into [128,256) of the LDS tile.
__global__ __launch_bounds__(256) void k4_out(
    const float* __restrict__ T, const float* __restrict__ S,
    const float* __restrict__ Wu2, const float* __restrict__ Wb2,
    const float* __restrict__ bu2, const float* __restrict__ bb2,
    float* __restrict__ out) {
    __shared__ float xs[64 * LS4];
    const int tid = threadIdx.x;
    const int lane = tid & 63;
    const int wv = __builtin_amdgcn_readfirstlane(tid >> 6);
    const int r0 = blockIdx.y * 64;
    const int cg = blockIdx.x * 16 + wv * 4;
    stage64(T, r0, xs, tid, LS4, 0);
    stage64(S, r0, xs, tid, LS4, 128);
    __syncthreads();
    float acc[4] = {0.f, 0.f, 0.f, 0.f};
    const float* wrowU[4];
    const float* wrowB[4];
#pragma unroll
    for (int c = 0; c < 4; ++c) {
        wrowU[c] = Wu2 + (cg + c) * 128;
        wrowB[c] = Wb2 + (cg + c) * 128;
    }
    accum<4>(xs, lane, LS4, 0, wrowU, acc);
    accum<4>(xs, lane, LS4, 128, wrowB, acc);
    float4 o;
    o.x = acc[0] + bu2[cg + 0] + 0.984375f * bb2[cg + 0];
    o.y = acc[1] + bu2[cg + 1] + 0.984375f * bb2[cg + 1];
    o.z = acc[2] + bu2[cg + 2] + 0.984375f * bb2[cg + 2];
    o.w = acc[3] + bu2[cg + 3] + 0.984375f * bb2[cg + 3];
    *reinterpret_cast<float4*>(&out[(size_t)(r0 + lane) * 128 + cg]) = o;
}

extern "C" void kernel_launch(void* const* d_in, const int* in_sizes, int n_in,
                              void* d_out, int out_size, void* d_ws,
                              size_t ws_size, hipStream_t stream) {
    const float* t = (const float*)d_in[0];
    const float* x = (const float*)d_in[1];
    const float* W_lin = (const float*)d_in[2];
    const float* b_lin = (const float*)d_in[3];
    const float* Wu1 = (const float*)d_in[4];
    const float* bu1 = (const float*)d_in[5];
    const float* Wu2 = (const float*)d_in[6];
    const float* bu2 = (const float*)d_in[7];
    const float* Wb1 = (const float*)d_in[8];
    const float* bb1 = (const float*)d_in[9];
    const float* Wb2 = (const float*)d_in[10];
    const float* bb2 = (const float*)d_in[11];
    float* out = (float*)d_out;

    float* ws = (float*)d_ws;
    float* h = ws;                  // [4096,128]
    float* T = ws + 1 * ROW_ELEMS;  // [4096,128]
    float* S = ws + 2 * ROW_ELEMS;  // [4096,128] (pre-scaled by 1/64)

    // K1: h (512 blocks, 2 waves/SIMD)
    k1_h<<<dim3(8, 64), 256, 0, stream>>>(x, W_lin, b_lin, t, h);
    // K2f: T + S' (768 blocks: 256 unary + 512 binary)
    k2_fused<<<dim3(12, 64), 256, 0, stream>>>(h, Wu1, bu1, Wb1, bb1, T, S);
    // K4: out (512 blocks)
    k4_out<<<dim3(8, 64), 256, 0, stream>>>(T, S, Wu2, Wb2, bu2, bb2, out);
    (void)in_sizes; (void)n_in; (void)out_size; (void)ws_size;
}

// Round 4
// 44.787 us; speedup vs baseline: 1.0722x; 1.0722x over previous
//
#include <hip/hip_runtime.h>

// Problem: N=64 graphs, K=64 nodes, C_IN=128, C=128, fp32.
// Pipeline (3 launches):
//   K1: h = x @ W_lin[:, :128].T + b_lin + t*W_lin[:,128]
//   K2f: heterogeneous grid over graphs:
//        binary blocks: A=h@Wb1L.T, Bb=h@Wb1R.T+bb1 (LDS only), then
//          U=exp2(k*A), V=exp2(k*Bb); S' = (63 - 2*sum_{i!=j} rcp(U_j*V_i+1))/64
//        unary blocks: T = tanh(h@Wu1.T + bu1)
//   K4: out = T@Wu2.T + S'@Wb2.T + bu2 + (63/64)*bb2
#define LS 132  // LDS row stride (dwords): (4l)%32 -> 8 dwords/bank (min) for b128
#define USTR 20 // U/V row stride: (20l)%32 -> 8 dwords/bank (min)
#define ROW_ELEMS 524288  // 4096*128
#define EXPC 2.8853900817779268f  // 2*log2(e)

__device__ __forceinline__ float sigterm(float x) {
    // 1/(exp(2x)+1)
    float e = __builtin_amdgcn_exp2f(x * EXPC);
    return __builtin_amdgcn_rcpf(e + 1.0f);
}
__device__ __forceinline__ float tanh_fast(float x) {
    return 1.0f - 2.0f * sigterm(x);
}

// Stage 64 rows x 128 cols of X (row stride 128) into xs[64][LS].
__device__ __forceinline__ void stage64(const float* __restrict__ X, int r0,
                                        float* __restrict__ xs, int tid) {
    const float4* src = reinterpret_cast<const float4*>(X + (size_t)r0 * 128);
#pragma unroll
    for (int p = 0; p < 8; ++p) {
        const int q = p * 256 + tid;  // 2048 float4s
        const int r = q >> 5;
        const int k4 = (q & 31) << 2;
        *reinterpret_cast<float4*>(&xs[r * LS + k4]) = src[q];
    }
}

// 128-k inner product: lane's row (LDS b128 reads) x NC wave-uniform weight
// rows (scalarized to s_load by uniformity).
template <int NC>
__device__ __forceinline__ void accum(const float* __restrict__ xs, int lane,
                                      const float* const (&wrow)[NC],
                                      float (&acc)[NC]) {
#pragma unroll 8
    for (int kq = 0; kq < 32; ++kq) {
        const float4 a =
            *reinterpret_cast<const float4*>(&xs[lane * LS + kq * 4]);
#pragma unroll
        for (int c = 0; c < NC; ++c) {
            const float* w = wrow[c] + kq * 4;
            acc[c] = fmaf(a.x, w[0], acc[c]);
            acc[c] = fmaf(a.y, w[1], acc[c]);
            acc[c] = fmaf(a.z, w[2], acc[c]);
            acc[c] = fmaf(a.w, w[3], acc[c]);
        }
    }
}

// K1: h = x@W_lin[:,:128].T + b_lin + t*W_lin[:,128]. 2 cols/wave,
// grid (16,64) = 1024 blocks -> 4 waves/SIMD.
__global__ __launch_bounds__(256) void k1_h(const float* __restrict__ x,
                                            const float* __restrict__ W_lin,
                                            const float* __restrict__ b_lin,
                                            const float* __restrict__ tp,
                                            float* __restrict__ h) {
    __shared__ float xs[64 * LS];
    const int tid = threadIdx.x;
    const int lane = tid & 63;
    const int wv = __builtin_amdgcn_readfirstlane(tid >> 6);
    const int r0 = blockIdx.y * 64;
    const int cg = blockIdx.x * 8 + wv * 2;
    stage64(x, r0, xs, tid);
    __syncthreads();
    float acc[2] = {0.f, 0.f};
    const float* wrow[2] = {W_lin + (cg + 0) * 129, W_lin + (cg + 1) * 129};
    accum<2>(xs, lane, wrow, acc);
    const float tv = tp[0];
    float2 o;
    o.x = acc[0] + b_lin[cg + 0] + tv * W_lin[(cg + 0) * 129 + 128];
    o.y = acc[1] + b_lin[cg + 1] + tv * W_lin[(cg + 1) * 129 + 128];
    *reinterpret_cast<float2*>(&h[(size_t)(r0 + lane) * 128 + cg]) = o;
}

// K2f: bx < 8  -> binary chunk of 16 channels for graph blockIdx.y
//      bx >= 8 -> unary T cols (32/block, 8/wave)
__global__ __launch_bounds__(256) void k2_fused(
    const float* __restrict__ h, const float* __restrict__ Wu1,
    const float* __restrict__ bu1, const float* __restrict__ Wb1,
    const float* __restrict__ bb1, float* __restrict__ T,
    float* __restrict__ S) {
    __shared__ float xs[64 * LS];
    __shared__ float us[64 * USTR];
    __shared__ float vs[64 * USTR];
    const int tid = threadIdx.x;
    const int lane = tid & 63;
    const int wv = __builtin_amdgcn_readfirstlane(tid >> 6);
    const int r0 = blockIdx.y * 64;  // graph n * 64
    const int bx = blockIdx.x;
    stage64(h, r0, xs, tid);
    __syncthreads();

    if (bx < 8) {  // ---- binary chunk (long pole; dispatched first) ----
        const int cb = bx * 16;
        const bool isB = wv >= 2;
        const int half = wv & 1;       // which 8-col half of the chunk
        const int c0 = cb + half * 8;  // GEMM col base within [0,128)
        float acc[8] = {0.f, 0.f, 0.f, 0.f, 0.f, 0.f, 0.f, 0.f};
        const float* wrow[8];
#pragma unroll
        for (int c = 0; c < 8; ++c)
            wrow[c] = Wb1 + (c0 + c) * 256 + (isB ? 128 : 0);
        accum<8>(xs, lane, wrow, acc);
        // U = exp2(k*A); V = exp2(k*(Bb + bb1))
        float e[8];
#pragma unroll
        for (int c = 0; c < 8; ++c) {
            const float v = isB ? (acc[c] + bb1[c0 + c]) : acc[c];
            e[c] = __builtin_amdgcn_exp2f(v * EXPC);
        }
        float* dstl = (isB ? vs : us) + lane * USTR + half * 8;
        *reinterpret_cast<float4*>(dstl) = make_float4(e[0], e[1], e[2], e[3]);
        *reinterpret_cast<float4*>(dstl + 4) =
            make_float4(e[4], e[5], e[6], e[7]);
        __syncthreads();  // block-uniform branch: all 4 waves arrive

        // S' phase: wave wv handles channels lc..lc+3; lane = node j.
        const int lc = wv * 4;
        const float4 u = *reinterpret_cast<const float4*>(&us[lane * USTR + lc]);
        float s0 = 0.f, s1 = 0.f, s2 = 0.f, s3 = 0.f;
#pragma unroll 8
        for (int i = 0; i < 64; ++i) {
            const float4 v = *reinterpret_cast<const float4*>(&vs[i * USTR + lc]);
            s0 += __builtin_amdgcn_rcpf(fmaf(u.x, v.x, 1.0f));
            s1 += __builtin_amdgcn_rcpf(fmaf(u.y, v.y, 1.0f));
            s2 += __builtin_amdgcn_rcpf(fmaf(u.z, v.z, 1.0f));
            s3 += __builtin_amdgcn_rcpf(fmaf(u.w, v.w, 1.0f));
        }
        const float4 vj = *reinterpret_cast<const float4*>(&vs[lane * USTR + lc]);
        float4 o;
        o.x = (63.0f - 2.0f * (s0 - __builtin_amdgcn_rcpf(fmaf(u.x, vj.x, 1.0f)))) * 0.015625f;
        o.y = (63.0f - 2.0f * (s1 - __builtin_amdgcn_rcpf(fmaf(u.y, vj.y, 1.0f)))) * 0.015625f;
        o.z = (63.0f - 2.0f * (s2 - __builtin_amdgcn_rcpf(fmaf(u.z, vj.z, 1.0f)))) * 0.015625f;
        o.w = (63.0f - 2.0f * (s3 - __builtin_amdgcn_rcpf(fmaf(u.w, vj.w, 1.0f)))) * 0.015625f;
        *reinterpret_cast<float4*>(&S[(size_t)(r0 + lane) * 128 + cb + lc]) = o;
    } else {  // ---- unary T ----
        const int cg = (bx - 8) * 32 + wv * 8;
        float acc[8] = {0.f, 0.f, 0.f, 0.f, 0.f, 0.f, 0.f, 0.f};
        const float* wrow[8];
#pragma unroll
        for (int c = 0; c < 8; ++c) wrow[c] = Wu1 + (cg + c) * 128;
        accum<8>(xs, lane, wrow, acc);
        float4 v0, v1;
        v0.x = tanh_fast(acc[0] + bu1[cg + 0]);
        v0.y = tanh_fast(acc[1] + bu1[cg + 1]);
        v0.z = tanh_fast(acc[2] + bu1[cg + 2]);
        v0.w = tanh_fast(acc[3] + bu1[cg + 3]);
        v1.x = tanh_fast(acc[4] + bu1[cg + 4]);
        v1.y = tanh_fast(acc[5] + bu1[cg + 5]);
        v1.z = tanh_fast(acc[6] + bu1[cg + 6]);
        v1.w = tanh_fast(acc[7] + bu1[cg + 7]);
        float* dst = T + (size_t)(r0 + lane) * 128 + cg;
        *reinterpret_cast<float4*>(dst) = v0;
        *reinterpret_cast<float4*>(dst + 4) = v1;
    }
}

// K4: out = T@Wu2.T + S'@Wb2.T + bu2 + (63/64)*bb2. Two sequential 128-k
// passes over ONE 34 KB LDS tile (keeps 4 blocks/CU). 2 cols/wave.
__global__ __launch_bounds__(256) void k4_out(
    const float* __restrict__ T, const float* __restrict__ S,
    const float* __restrict__ Wu2, const float* __restrict__ Wb2,
    const float* __restrict__ bu2, const float* __restrict__ bb2,
    float* __restrict__ out) {
    __shared__ float xs[64 * LS];
    const int tid = threadIdx.x;
    const int lane = tid & 63;
    const int wv = __builtin_amdgcn_readfirstlane(tid >> 6);
    const int r0 = blockIdx.y * 64;
    const int cg = blockIdx.x * 8 + wv * 2;
    stage64(T, r0, xs, tid);
    __syncthreads();
    float acc[2] = {0.f, 0.f};
    {
        const float* wrow[2] = {Wu2 + (cg + 0) * 128, Wu2 + (cg + 1) * 128};
        accum<2>(xs, lane, wrow, acc);
    }
    __syncthreads();  // done reading T tile
    stage64(S, r0, xs, tid);
    __syncthreads();
    {
        const float* wrow[2] = {Wb2 + (cg + 0) * 128, Wb2 + (cg + 1) * 128};
        accum<2>(xs, lane, wrow, acc);
    }
    float2 o;
    o.x = acc[0] + bu2[cg + 0] + 0.984375f * bb2[cg + 0];
    o.y = acc[1] + bu2[cg + 1] + 0.984375f * bb2[cg + 1];
    *reinterpret_cast<float2*>(&out[(size_t)(r0 + lane) * 128 + cg]) = o;
}

extern "C" void kernel_launch(void* const* d_in, const int* in_sizes, int n_in,
                              void* d_out, int out_size, void* d_ws,
                              size_t ws_size, hipStream_t stream) {
    const float* t = (const float*)d_in[0];
    const float* x = (const float*)d_in[1];
    const float* W_lin = (const float*)d_in[2];
    const float* b_lin = (const float*)d_in[3];
    const float* Wu1 = (const float*)d_in[4];
    const float* bu1 = (const float*)d_in[5];
    const float* Wu2 = (const float*)d_in[6];
    const float* bu2 = (const float*)d_in[7];
    const float* Wb1 = (const float*)d_in[8];
    const float* bb1 = (const float*)d_in[9];
    const float* Wb2 = (const float*)d_in[10];
    const float* bb2 = (const float*)d_in[11];
    float* out = (float*)d_out;

    float* ws = (float*)d_ws;
    float* h = ws;                  // [4096,128]
    float* T = ws + 1 * ROW_ELEMS;  // [4096,128]
    float* S = ws + 2 * ROW_ELEMS;  // [4096,128] (pre-scaled by 1/64)

    // K1: h (1024 blocks, 4 waves/SIMD)
    k1_h<<<dim3(16, 64), 256, 0, stream>>>(x, W_lin, b_lin, t, h);
    // K2f: S' + T (768 blocks: 512 binary first, 256 unary)
    k2_fused<<<dim3(12, 64), 256, 0, stream>>>(h, Wu1, bu1, Wb1, bb1, T, S);
    // K4: out (1024 blocks, 4 waves/SIMD)
    k4_out<<<dim3(16, 64), 256, 0, stream>>>(T, S, Wu2, Wb2, bu2, bb2, out);
    (void)in_sizes; (void)n_in; (void)out_size; (void)ws_size;
}

// Round 5
// 38.126 us; speedup vs baseline: 1.2595x; 1.1747x over previous
//
#include <hip/hip_runtime.h>

// Problem: N=64 graphs, K=64 nodes, C_IN=128, C=128, fp32.
// Pipeline (3 launches):
//   K1: h = x @ W_lin[:, :128].T + b_lin + t*W_lin[:,128]
//   K2f: heterogeneous grid over graphs:
//        binary blocks: A=h@Wb1L.T, Bb=h@Wb1R.T+bb1 (LDS only), then
//          U=exp2(k*A), V=exp2(k*Bb); S' = (63 - 2*sum_{i!=j} rcp(U_j*V_i+1))/64
//        unary blocks: T = tanh(h@Wu1.T + bu1)
//        Weights for the block's 32 GEMM cols are staged in LDS and read via
//        wave-uniform broadcasts (replaces batched s_load latency stalls).
//   K4: out = T@Wu2.T + S'@Wb2.T + bu2 + (63/64)*bb2
#define LS 132  // LDS row stride (dwords): (4l)%32 -> 8 dwords/bank (min) for b128
#define USTR 20 // U/V row stride: (20l)%32 -> 8 dwords/bank (min)
#define ROW_ELEMS 524288  // 4096*128
#define EXPC 2.8853900817779268f  // 2*log2(e)

__device__ __forceinline__ float sigterm(float x) {
    // 1/(exp(2x)+1)
    float e = __builtin_amdgcn_exp2f(x * EXPC);
    return __builtin_amdgcn_rcpf(e + 1.0f);
}
__device__ __forceinline__ float tanh_fast(float x) {
    return 1.0f - 2.0f * sigterm(x);
}

// Stage 64 rows x 128 cols of X (row stride 128) into xs[64][LS].
__device__ __forceinline__ void stage64(const float* __restrict__ X, int r0,
                                        float* __restrict__ xs, int tid) {
    const float4* src = reinterpret_cast<const float4*>(X + (size_t)r0 * 128);
#pragma unroll
    for (int p = 0; p < 8; ++p) {
        const int q = p * 256 + tid;  // 2048 float4s
        const int r = q >> 5;
        const int k4 = (q & 31) << 2;
        *reinterpret_cast<float4*>(&xs[r * LS + k4]) = src[q];
    }
}

// 128-k inner product vs NC LDS-staged weight cols (wave-uniform broadcast
// reads); lane's activation row via per-lane b128 (bank-balanced).
template <int NC>
__device__ __forceinline__ void accum_lds(const float* __restrict__ xs,
                                          const float* __restrict__ wt,
                                          int lane, int wc0,
                                          float (&acc)[NC]) {
#pragma unroll 8
    for (int kq = 0; kq < 32; ++kq) {
        const float4 a =
            *reinterpret_cast<const float4*>(&xs[lane * LS + kq * 4]);
#pragma unroll
        for (int c = 0; c < NC; ++c) {
            const float4 w = *reinterpret_cast<const float4*>(
                &wt[(wc0 + c) * 128 + kq * 4]);
            acc[c] = fmaf(a.x, w.x, acc[c]);
            acc[c] = fmaf(a.y, w.y, acc[c]);
            acc[c] = fmaf(a.z, w.z, acc[c]);
            acc[c] = fmaf(a.w, w.w, acc[c]);
        }
    }
}

// s_load-based variant (K1/K4: small per-wave col counts, 4 blocks/CU hide it)
template <int NC>
__device__ __forceinline__ void accum(const float* __restrict__ xs, int lane,
                                      const float* const (&wrow)[NC],
                                      float (&acc)[NC]) {
#pragma unroll 8
    for (int kq = 0; kq < 32; ++kq) {
        const float4 a =
            *reinterpret_cast<const float4*>(&xs[lane * LS + kq * 4]);
#pragma unroll
        for (int c = 0; c < NC; ++c) {
            const float* w = wrow[c] + kq * 4;
            acc[c] = fmaf(a.x, w[0], acc[c]);
            acc[c] = fmaf(a.y, w[1], acc[c]);
            acc[c] = fmaf(a.z, w[2], acc[c]);
            acc[c] = fmaf(a.w, w[3], acc[c]);
        }
    }
}

// K1: h = x@W_lin[:,:128].T + b_lin + t*W_lin[:,128]. 2 cols/wave,
// grid (16,64) = 1024 blocks -> 4 waves/SIMD.
__global__ __launch_bounds__(256) void k1_h(const float* __restrict__ x,
                                            const float* __restrict__ W_lin,
                                            const float* __restrict__ b_lin,
                                            const float* __restrict__ tp,
                                            float* __restrict__ h) {
    __shared__ float xs[64 * LS];
    const int tid = threadIdx.x;
    const int lane = tid & 63;
    const int wv = __builtin_amdgcn_readfirstlane(tid >> 6);
    const int r0 = blockIdx.y * 64;
    const int cg = blockIdx.x * 8 + wv * 2;
    stage64(x, r0, xs, tid);
    __syncthreads();
    float acc[2] = {0.f, 0.f};
    const float* wrow[2] = {W_lin + (cg + 0) * 129, W_lin + (cg + 1) * 129};
    accum<2>(xs, lane, wrow, acc);
    const float tv = tp[0];
    float2 o;
    o.x = acc[0] + b_lin[cg + 0] + tv * W_lin[(cg + 0) * 129 + 128];
    o.y = acc[1] + b_lin[cg + 1] + tv * W_lin[(cg + 1) * 129 + 128];
    *reinterpret_cast<float2*>(&h[(size_t)(r0 + lane) * 128 + cg]) = o;
}

// K2f: bx < 8  -> binary chunk of 16 channels for graph blockIdx.y
//      bx >= 8 -> unary T cols (32/block, 8/wave)
// LDS: xs[64*LS] + wt[32*128] = 50.2 KB -> 3 blocks/CU. us/vs alias xs
// (xs dead after GEMM; barrier-protected).
__global__ __launch_bounds__(256) void k2_fused(
    const float* __restrict__ h, const float* __restrict__ Wu1,
    const float* __restrict__ bu1, const float* __restrict__ Wb1,
    const float* __restrict__ bb1, float* __restrict__ T,
    float* __restrict__ S) {
    __shared__ float smem[64 * LS + 32 * 128];
    float* xs = smem;
    float* wt = smem + 64 * LS;
    float* us = smem;               // alias: first 1280 floats of xs region
    float* vs = smem + 64 * USTR;   // next 1280
    const int tid = threadIdx.x;
    const int lane = tid & 63;
    const int wv = __builtin_amdgcn_readfirstlane(tid >> 6);
    const int r0 = blockIdx.y * 64;  // graph n * 64
    const int bx = blockIdx.x;
    stage64(h, r0, xs, tid);
    // Stage this block's 32 weight rows (binary: A rows cb..cb+15 from
    // Wb1[:, :128], B rows from Wb1[:, 128:256]; unary: Wu1 rows cg0..cg0+31).
    {
        const int cb = bx < 8 ? bx * 16 : 0;
        const int cg0 = bx >= 8 ? (bx - 8) * 32 : 0;
#pragma unroll
        for (int p = 0; p < 4; ++p) {
            const int q = p * 256 + tid;  // 1024 float4s
            const int row = q >> 5;
            const int k4 = (q & 31) << 2;
            const float* src;
            if (bx < 8)
                src = (row < 16) ? (Wb1 + (cb + row) * 256 + k4)
                                 : (Wb1 + (cb + row - 16) * 256 + 128 + k4);
            else
                src = Wu1 + (cg0 + row) * 128 + k4;
            *reinterpret_cast<float4*>(&wt[row * 128 + k4]) =
                *reinterpret_cast<const float4*>(src);
        }
    }
    __syncthreads();

    if (bx < 8) {  // ---- binary chunk (long pole; dispatched first) ----
        const int cb = bx * 16;
        const bool isB = wv >= 2;
        const int half = wv & 1;       // which 8-col half of the chunk
        const int c0 = cb + half * 8;  // GEMM col base within [0,128)
        const int wc0 = (isB ? 16 : 0) + half * 8;  // wt-local col base
        float acc[8] = {0.f, 0.f, 0.f, 0.f, 0.f, 0.f, 0.f, 0.f};
        accum_lds<8>(xs, wt, lane, wc0, acc);
        // U = exp2(k*A); V = exp2(k*(Bb + bb1))
        float e[8];
#pragma unroll
        for (int c = 0; c < 8; ++c) {
            const float v = isB ? (acc[c] + bb1[c0 + c]) : acc[c];
            e[c] = __builtin_amdgcn_exp2f(v * EXPC);
        }
        __syncthreads();  // all waves done reading xs; safe to overwrite
        float* dstl = (isB ? vs : us) + lane * USTR + half * 8;
        *reinterpret_cast<float4*>(dstl) = make_float4(e[0], e[1], e[2], e[3]);
        *reinterpret_cast<float4*>(dstl + 4) =
            make_float4(e[4], e[5], e[6], e[7]);
        __syncthreads();

        // S' phase: wave wv handles channels lc..lc+3; lane = node j.
        const int lc = wv * 4;
        const float4 u = *reinterpret_cast<const float4*>(&us[lane * USTR + lc]);
        float s0 = 0.f, s1 = 0.f, s2 = 0.f, s3 = 0.f;
#pragma unroll 8
        for (int i = 0; i < 64; ++i) {
            const float4 v = *reinterpret_cast<const float4*>(&vs[i * USTR + lc]);
            s0 += __builtin_amdgcn_rcpf(fmaf(u.x, v.x, 1.0f));
            s1 += __builtin_amdgcn_rcpf(fmaf(u.y, v.y, 1.0f));
            s2 += __builtin_amdgcn_rcpf(fmaf(u.z, v.z, 1.0f));
            s3 += __builtin_amdgcn_rcpf(fmaf(u.w, v.w, 1.0f));
        }
        const float4 vj = *reinterpret_cast<const float4*>(&vs[lane * USTR + lc]);
        float4 o;
        o.x = (63.0f - 2.0f * (s0 - __builtin_amdgcn_rcpf(fmaf(u.x, vj.x, 1.0f)))) * 0.015625f;
        o.y = (63.0f - 2.0f * (s1 - __builtin_amdgcn_rcpf(fmaf(u.y, vj.y, 1.0f)))) * 0.015625f;
        o.z = (63.0f - 2.0f * (s2 - __builtin_amdgcn_rcpf(fmaf(u.z, vj.z, 1.0f)))) * 0.015625f;
        o.w = (63.0f - 2.0f * (s3 - __builtin_amdgcn_rcpf(fmaf(u.w, vj.w, 1.0f)))) * 0.015625f;
        *reinterpret_cast<float4*>(&S[(size_t)(r0 + lane) * 128 + cb + lc]) = o;
    } else {  // ---- unary T ----
        const int cg = (bx - 8) * 32 + wv * 8;
        float acc[8] = {0.f, 0.f, 0.f, 0.f, 0.f, 0.f, 0.f, 0.f};
        accum_lds<8>(xs, wt, lane, wv * 8, acc);
        float4 v0, v1;
        v0.x = tanh_fast(acc[0] + bu1[cg + 0]);
        v0.y = tanh_fast(acc[1] + bu1[cg + 1]);
        v0.z = tanh_fast(acc[2] + bu1[cg + 2]);
        v0.w = tanh_fast(acc[3] + bu1[cg + 3]);
        v1.x = tanh_fast(acc[4] + bu1[cg + 4]);
        v1.y = tanh_fast(acc[5] + bu1[cg + 5]);
        v1.z = tanh_fast(acc[6] + bu1[cg + 6]);
        v1.w = tanh_fast(acc[7] + bu1[cg + 7]);
        float* dst = T + (size_t)(r0 + lane) * 128 + cg;
        *reinterpret_cast<float4*>(dst) = v0;
        *reinterpret_cast<float4*>(dst + 4) = v1;
    }
}

// K4: out = T@Wu2.T + S'@Wb2.T + bu2 + (63/64)*bb2. Two sequential 128-k
// passes over ONE 34 KB LDS tile (keeps 4 blocks/CU). 2 cols/wave.
__global__ __launch_bounds__(256) void k4_out(
    const float* __restrict__ T, const float* __restrict__ S,
    const float* __restrict__ Wu2, const float* __restrict__ Wb2,
    const float* __restrict__ bu2, const float* __restrict__ bb2,
    float* __restrict__ out) {
    __shared__ float xs[64 * LS];
    const int tid = threadIdx.x;
    const int lane = tid & 63;
    const int wv = __builtin_amdgcn_readfirstlane(tid >> 6);
    const int r0 = blockIdx.y * 64;
    const int cg = blockIdx.x * 8 + wv * 2;
    stage64(T, r0, xs, tid);
    __syncthreads();
    float acc[2] = {0.f, 0.f};
    {
        const float* wrow[2] = {Wu2 + (cg + 0) * 128, Wu2 + (cg + 1) * 128};
        accum<2>(xs, lane, wrow, acc);
    }
    __syncthreads();  // done reading T tile
    stage64(S, r0, xs, tid);
    __syncthreads();
    {
        const float* wrow[2] = {Wb2 + (cg + 0) * 128, Wb2 + (cg + 1) * 128};
        accum<2>(xs, lane, wrow, acc);
    }
    float2 o;
    o.x = acc[0] + bu2[cg + 0] + 0.984375f * bb2[cg + 0];
    o.y = acc[1] + bu2[cg + 1] + 0.984375f * bb2[cg + 1];
    *reinterpret_cast<float2*>(&out[(size_t)(r0 + lane) * 128 + cg]) = o;
}

extern "C" void kernel_launch(void* const* d_in, const int* in_sizes, int n_in,
                              void* d_out, int out_size, void* d_ws,
                              size_t ws_size, hipStream_t stream) {
    const float* t = (const float*)d_in[0];
    const float* x = (const float*)d_in[1];
    const float* W_lin = (const float*)d_in[2];
    const float* b_lin = (const float*)d_in[3];
    const float* Wu1 = (const float*)d_in[4];
    const float* bu1 = (const float*)d_in[5];
    const float* Wu2 = (const float*)d_in[6];
    const float* bu2 = (const float*)d_in[7];
    const float* Wb1 = (const float*)d_in[8];
    const float* bb1 = (const float*)d_in[9];
    const float* Wb2 = (const float*)d_in[10];
    const float* bb2 = (const float*)d_in[11];
    float* out = (float*)d_out;

    float* ws = (float*)d_ws;
    float* h = ws;                  // [4096,128]
    float* T = ws + 1 * ROW_ELEMS;  // [4096,128]
    float* S = ws + 2 * ROW_ELEMS;  // [4096,128] (pre-scaled by 1/64)

    // K1: h (1024 blocks, 4 waves/SIMD)
    k1_h<<<dim3(16, 64), 256, 0, stream>>>(x, W_lin, b_lin, t, h);
    // K2f: S' + T (768 blocks: 512 binary first, 256 unary)
    k2_fused<<<dim3(12, 64), 256, 0, stream>>>(h, Wu1, bu1, Wb1, bb1, T, S);
    // K4: out (1024 blocks, 4 waves/SIMD)
    k4_out<<<dim3(16, 64), 256, 0, stream>>>(T, S, Wu2, Wb2, bu2, bb2, out);
    (void)in_sizes; (void)n_in; (void)out_size; (void)ws_size;
}